// Round 1
// baseline (525.019 us; speedup 1.0000x reference)
//
#include <hip/hip_runtime.h>
#include <hip/hip_bf16.h>
#include <cstddef>
#include <cstdint>

#define NBLK(n, b) (((n) + (b) - 1) / (b))

typedef __attribute__((ext_vector_type(8))) short short8;
typedef __attribute__((ext_vector_type(4))) float f32x4;
typedef __attribute__((ext_vector_type(2))) float f32x2;

__device__ inline unsigned short f2bf(float f) {
  union { float f; unsigned u; } v; v.f = f;
  unsigned u = v.u;
  u += 0x7FFFu + ((u >> 16) & 1u);  // RNE
  return (unsigned short)(u >> 16);
}
__device__ inline float bflo(unsigned u) { union { unsigned u; float f; } v; v.u = u << 16; return v.f; }
__device__ inline float bfhi(unsigned u) { union { unsigned u; float f; } v; v.u = u & 0xFFFF0000u; return v.f; }

// CSR bucket sort: buckets of 512 nodes; node ids < 2^17 (N=100K).
// key = src | (localDst << 17) fits u32. Fixed-capacity padded buckets.
#define BSHIFT 9
#define BSIZE 512
#define CAPSHIFT 14
#define CAP 16384
#define ECHUNK 2048

// All bf16 feature tensors live in SLICE-TRANSPOSED layout:
//   element (node, ch) at half-index ((ch>>4) * N + node) * 16 + (ch & 15)
// i.e. T[g][N][16ch], one 32 B row per node per 16-ch slice. Slice g = 3.2 MB
// (bf16, N=100K) -> fits one XCD's 4 MB L2. Aggregation blocks are dispatched
// with slice = blockIdx.x & 7 so each XCD only ever gathers its own slice.

// ---------------- cast x -> bf16 sliced layout, prep packed weights ----------------
__global__ __launch_bounds__(256) void k_cast(
    const float* __restrict__ x, unsigned* __restrict__ xT, int N,
    const float* __restrict__ W1l, const float* __restrict__ W1r, unsigned short* __restrict__ Wb1,
    const float* __restrict__ W2l, const float* __restrict__ W2r, unsigned short* __restrict__ Wb2,
    const float* __restrict__ W3l, const float* __restrict__ W3r, unsigned short* __restrict__ Wb3) {
  int t = threadIdx.x;
  int b = blockIdx.x;
  int gCast = (N * 64 + 255) >> 8;
  if (b < gCast) {
    int i = b * 256 + t;
    if (i < N * 64) {
      float2 v = *(const float2*)(x + (size_t)i * 2);
      int node = i >> 6, j = i & 63;
      // word covers channels {2j, 2j+1}; slice g = j>>3, word-in-slice = j&7
      xT[((size_t)(j >> 3) * N + node) * 8 + (j & 7)] =
          (unsigned)f2bf(v.x) | ((unsigned)f2bf(v.y) << 16);
    }
    return;
  }
  b -= gCast;
  int ii = b * 256 + t;
  const float *Wl, *Wr; unsigned short* Wb;
  if (ii < 128 * 256) { Wl = W1l; Wr = W1r; Wb = Wb1; }
  else if (ii < 256 * 256) { Wl = W2l; Wr = W2r; Wb = Wb2; ii -= 128 * 256; }
  else { Wl = W3l; Wr = W3r; Wb = Wb3; ii -= 256 * 256; }
  int nrow = ii >> 8, k = ii & 255;
  float v = (k < 128) ? Wr[nrow * 128 + k] : Wl[nrow * 128 + (k - 128)];
  Wb[ii] = f2bf(v);
}

// ---------------- edge scatter into padded buckets ----------------
__global__ __launch_bounds__(256) void k_scatter(
    const void* __restrict__ edges, int* __restrict__ bucketCursor,
    unsigned* __restrict__ bucketed, int E, int NB) {
  __shared__ int h[1024];
  __shared__ int base2[1024];
  int t = threadIdx.x;
  int b = blockIdx.x;

  const unsigned* e32 = (const unsigned*)edges;
  int is64 = 1;
#pragma unroll
  for (int i = 0; i < 16; ++i)
    if (e32[2 * i + 1] != 0u) is64 = 0;

  for (int i = t; i < NB; i += 256) h[i] = 0;
  __syncthreads();
  int base_e = b * ECHUNK;
  unsigned key[8];
  int bkt[8];
#pragma unroll
  for (int k = 0; k < 8; ++k) {
    int e = base_e + k * 256 + t;
    bkt[k] = -1;
    if (e < E) {
      int s, d;
      if (is64) {
        s = (int)((const long long*)edges)[e];
        d = (int)((const long long*)edges)[(size_t)E + e];
      } else {
        s = ((const int*)edges)[e];
        d = ((const int*)edges)[(size_t)E + e];
      }
      bkt[k] = d >> BSHIFT;
      key[k] = (unsigned)s | ((unsigned)(d & (BSIZE - 1)) << 17);
      atomicAdd(&h[bkt[k]], 1);
    }
  }
  __syncthreads();
  for (int i = t; i < NB; i += 256) {
    int c = h[i];
    base2[i] = c ? atomicAdd(&bucketCursor[i], c) : 0;
    h[i] = 0;
  }
  __syncthreads();
#pragma unroll
  for (int k = 0; k < 8; ++k) {
    if (bkt[k] >= 0) {
      int r = atomicAdd(&h[bkt[k]], 1);
      int pos = base2[bkt[k]] + r;
      if (pos < CAP)
        bucketed[((size_t)bkt[k] << CAPSHIFT) + pos] = key[k];
    }
  }
}

// ---------------- per-bucket CSR: rowStart + deg + srcSorted (padded layout) ----------------
__global__ __launch_bounds__(256) void k_csr(const unsigned* __restrict__ bucketed,
                                             const int* __restrict__ bucketCursor,
                                             int* __restrict__ rowStart, int* __restrict__ deg,
                                             int* __restrict__ srcSorted, int N, int NB) {
  __shared__ int h[512];
  __shared__ int excl[512];
  __shared__ int sd[256];
  int b = blockIdx.x;
  int t = threadIdx.x;
  int nodeBase = b << BSHIFT;
  int nNode = min(BSIZE, N - nodeBase);
  int cnt = min(bucketCursor[b], CAP);
  size_t s0 = (size_t)b << CAPSHIFT;
  h[t * 2] = 0; h[t * 2 + 1] = 0;
  __syncthreads();
  for (int i = t; i < cnt; i += 256) {
    int ld = bucketed[s0 + i] >> 17;
    atomicAdd(&h[ld], 1);
  }
  __syncthreads();
  int a0 = h[t * 2], a1 = h[t * 2 + 1];
  int s = a0 + a1;
  sd[t] = s;
  __syncthreads();
  for (int off = 1; off < 256; off <<= 1) {
    int xv = (t >= off) ? sd[t - off] : 0;
    __syncthreads();
    sd[t] += xv;
    __syncthreads();
  }
  int run = sd[t] - s;
  excl[t * 2] = run;
  excl[t * 2 + 1] = run + a0;
  if (t * 2 < nNode) {
    rowStart[nodeBase + t * 2] = (int)s0 + run;
    deg[nodeBase + t * 2] = a0;
  }
  if (t * 2 + 1 < nNode) {
    rowStart[nodeBase + t * 2 + 1] = (int)s0 + run + a0;
    deg[nodeBase + t * 2 + 1] = a1;
  }
  h[t * 2] = 0; h[t * 2 + 1] = 0;
  __syncthreads();
  for (int i = t; i < cnt; i += 256) {
    unsigned u = bucketed[s0 + i];
    int ld = u >> 17;
    int r = atomicAdd(&h[ld], 1);
    srcSorted[s0 + excl[ld] + r] = (int)(u & 0x1FFFFu);
  }
}

// ---------------- slice-sharded mean aggregation (128-ch layers) ----------------
// grid.x = 8 * ceil(N/128); slice g = bid & 7 (XCD-affine via %8 round-robin),
// node range = (bid>>3)*128. Two lanes per node (h = 8-ch half); per-lane serial
// edge walk, 8-deep unrolled gathers, no cross-lane reduce.
__global__ __launch_bounds__(256) void k_agg_slice(
    const uint4* __restrict__ inT, const int* __restrict__ rowStart,
    const int* __restrict__ deg, const int* __restrict__ srcs,
    uint4* __restrict__ outT, int n) {
  int g = blockIdx.x & 7;
  int node = ((blockIdx.x >> 3) << 7) + (threadIdx.x >> 1);
  int h = threadIdx.x & 1;
  if (node >= n) return;
  int dg = deg[node];
  f32x2 acc0 = {0.f, 0.f}, acc1 = {0.f, 0.f}, acc2 = {0.f, 0.f}, acc3 = {0.f, 0.f};
  const uint4* base = inT + (size_t)g * n * 2 + h;
  if (dg > 0) {
    int r0 = rowStart[node];
    int r1 = r0 + dg;
    for (int b = r0; b < r1; b += 8) {
      int s[8];
      uint4 v[8];
#pragma unroll
      for (int i = 0; i < 8; ++i) s[i] = srcs[min(b + i, r1 - 1)] & 0x1FFFF;
#pragma unroll
      for (int i = 0; i < 8; ++i) v[i] = base[(size_t)s[i] * 2];
#pragma unroll
      for (int i = 0; i < 8; ++i) {
        if (b + i < r1) {
          f32x2 t0 = {bflo(v[i].x), bfhi(v[i].x)};
          f32x2 t1 = {bflo(v[i].y), bfhi(v[i].y)};
          f32x2 t2 = {bflo(v[i].z), bfhi(v[i].z)};
          f32x2 t3 = {bflo(v[i].w), bfhi(v[i].w)};
          acc0 += t0; acc1 += t1; acc2 += t2; acc3 += t3;
        }
      }
    }
  }
  float sc = 1.0f / (float)max(dg, 1);
  uint4 o;
  o.x = (unsigned)f2bf(acc0.x * sc) | ((unsigned)f2bf(acc0.y * sc) << 16);
  o.y = (unsigned)f2bf(acc1.x * sc) | ((unsigned)f2bf(acc1.y * sc) << 16);
  o.z = (unsigned)f2bf(acc2.x * sc) | ((unsigned)f2bf(acc2.y * sc) << 16);
  o.w = (unsigned)f2bf(acc3.x * sc) | ((unsigned)f2bf(acc3.y * sc) << 16);
  outT[((size_t)g * n + node) * 2 + h] = o;
}

// ---------------- MFMA GEMM: out = self@Wr.T + mean@Wl.T + b (layers 1-2) ----------------
// A operands read from sliced layout; output written to sliced layout (bf16).
template <int H, bool RELU>
__global__ __launch_bounds__(256) void k_gemm(
    const unsigned short* __restrict__ selfT, const unsigned short* __restrict__ meanT,
    const unsigned short* __restrict__ Wb, const float* __restrict__ bias,
    unsigned short* __restrict__ outT, int n) {
  constexpr int TN = H / 32;
  int lane = threadIdx.x & 63;
  int w = threadIdx.x >> 6;
  int wr = w & 1, wc = w >> 1;
  int nodeBase = blockIdx.x * 128 + wr * 64;
  int colBase = wc * (H / 2);
  int l15 = lane & 15, quad = lane >> 4;

  f32x4 acc[4][TN];
#pragma unroll
  for (int t = 0; t < 4; ++t)
#pragma unroll
    for (int j = 0; j < TN; ++j) acc[t][j] = (f32x4){0.f, 0.f, 0.f, 0.f};

#pragma unroll
  for (int c = 0; c < 8; ++c) {
    const unsigned short* A = (c < 4) ? selfT : meanT;
    int ko = (c & 3) * 32 + quad * 8;
    int gk = ko >> 4;    // 16-ch slice
    int wo = ko & 15;    // 0 or 8
    short8 af[4], bfr[TN];
#pragma unroll
    for (int t = 0; t < 4; ++t) {
      int row = min(nodeBase + t * 16 + l15, n - 1);
      af[t] = *(const short8*)(A + ((size_t)gk * n + row) * 16 + wo);
    }
#pragma unroll
    for (int j = 0; j < TN; ++j) {
      int cn = colBase + j * 16 + l15;
      bfr[j] = *(const short8*)(Wb + (size_t)cn * 256 + c * 32 + quad * 8);
    }
#pragma unroll
    for (int t = 0; t < 4; ++t)
#pragma unroll
      for (int j = 0; j < TN; ++j)
        acc[t][j] = __builtin_amdgcn_mfma_f32_16x16x32_bf16(af[t], bfr[j], acc[t][j], 0, 0, 0);
  }

#pragma unroll
  for (int j = 0; j < TN; ++j) {
    int col = colBase + j * 16 + l15;
    int gc = col >> 4;  // = wc*4 + j
    float bv = bias[col];
#pragma unroll
    for (int t = 0; t < 4; ++t) {
#pragma unroll
      for (int r = 0; r < 4; ++r) {
        int row = nodeBase + t * 16 + quad * 4 + r;
        if (row < n) {
          float v = acc[t][j][r] + bv;
          if (RELU) v = fmaxf(v, 0.f);
          outT[((size_t)gc * n + row) * 16 + l15] = f2bf(v);
        }
      }
    }
  }
}

// ---------------- layer-3 combined transform: out = h2@W3r.T + b3 (fp32); y3T = h2@W3l.T (bf16 sliced) ----------------
__global__ __launch_bounds__(256) void k_gemm3_both(
    const unsigned short* __restrict__ A,    // h2T sliced
    const unsigned short* __restrict__ Wb3,  // [64][256]: self half +0, mean half +128
    const float* __restrict__ bias,
    float* __restrict__ outp, unsigned short* __restrict__ y3T, int n) {
  int lane = threadIdx.x & 63;
  int w = threadIdx.x >> 6;
  int wr = w & 1, wc = w >> 1;
  int nodeBase = blockIdx.x * 128 + wr * 64;
  int l15 = lane & 15, quad = lane >> 4;
  int woff = wc ? 128 : 0;
  f32x4 acc[4][4];
#pragma unroll
  for (int t = 0; t < 4; ++t)
#pragma unroll
    for (int j = 0; j < 4; ++j) acc[t][j] = (f32x4){0.f, 0.f, 0.f, 0.f};
#pragma unroll
  for (int c = 0; c < 4; ++c) {
    int ko = c * 32 + quad * 8;
    int gk = ko >> 4;
    int wo = ko & 15;
    short8 af[4], bfr[4];
#pragma unroll
    for (int t = 0; t < 4; ++t) {
      int row = min(nodeBase + t * 16 + l15, n - 1);
      af[t] = *(const short8*)(A + ((size_t)gk * n + row) * 16 + wo);
    }
#pragma unroll
    for (int j = 0; j < 4; ++j) {
      int cn = j * 16 + l15;
      bfr[j] = *(const short8*)(Wb3 + (size_t)cn * 256 + woff + c * 32 + quad * 8);
    }
#pragma unroll
    for (int t = 0; t < 4; ++t)
#pragma unroll
      for (int j = 0; j < 4; ++j)
        acc[t][j] = __builtin_amdgcn_mfma_f32_16x16x32_bf16(af[t], bfr[j], acc[t][j], 0, 0, 0);
  }
#pragma unroll
  for (int j = 0; j < 4; ++j) {
    int col = j * 16 + l15;
    float bv = wc ? 0.f : bias[col];
#pragma unroll
    for (int t = 0; t < 4; ++t) {
#pragma unroll
      for (int r = 0; r < 4; ++r) {
        int row = nodeBase + t * 16 + quad * 4 + r;
        if (row < n) {
          float v = acc[t][j][r] + bv;
          if (wc) y3T[((size_t)j * n + row) * 16 + l15] = f2bf(v);
          else outp[(size_t)row * 64 + col] = v;
        }
      }
    }
  }
}

// ---------------- layer-3 slice-sharded aggregate: out += mean(y3 over in-neighbors) ----------------
// grid.x = 4 * ceil(N/128); slice g = bid & 3 -> XCD = bid%8 puts slice g on XCDs {g, g+4}.
__global__ __launch_bounds__(256) void k_agg64_slice(
    const uint4* __restrict__ y3T, const int* __restrict__ rowStart,
    const int* __restrict__ deg, const int* __restrict__ srcs,
    float* __restrict__ outp, int n) {
  int g = blockIdx.x & 3;
  int node = ((blockIdx.x >> 2) << 7) + (threadIdx.x >> 1);
  int h = threadIdx.x & 1;
  if (node >= n) return;
  int dg = deg[node];
  if (dg == 0) return;
  int r0 = rowStart[node];
  int r1 = r0 + dg;
  f32x2 acc0 = {0.f, 0.f}, acc1 = {0.f, 0.f}, acc2 = {0.f, 0.f}, acc3 = {0.f, 0.f};
  const uint4* base = y3T + (size_t)g * n * 2 + h;
  for (int b = r0; b < r1; b += 8) {
    int s[8];
    uint4 v[8];
#pragma unroll
    for (int i = 0; i < 8; ++i) s[i] = srcs[min(b + i, r1 - 1)] & 0x1FFFF;
#pragma unroll
    for (int i = 0; i < 8; ++i) v[i] = base[(size_t)s[i] * 2];
#pragma unroll
    for (int i = 0; i < 8; ++i) {
      if (b + i < r1) {
        f32x2 t0 = {bflo(v[i].x), bfhi(v[i].x)};
        f32x2 t1 = {bflo(v[i].y), bfhi(v[i].y)};
        f32x2 t2 = {bflo(v[i].z), bfhi(v[i].z)};
        f32x2 t3 = {bflo(v[i].w), bfhi(v[i].w)};
        acc0 += t0; acc1 += t1; acc2 += t2; acc3 += t3;
      }
    }
  }
  float sc = 1.0f / (float)dg;
  float* op = outp + (size_t)node * 64 + g * 16 + h * 8;
  float4 a = *(float4*)op;
  float4 c = *(float4*)(op + 4);
  a.x += acc0.x * sc; a.y += acc0.y * sc; a.z += acc1.x * sc; a.w += acc1.y * sc;
  c.x += acc2.x * sc; c.y += acc2.y * sc; c.z += acc3.x * sc; c.w += acc3.y * sc;
  *(float4*)op = a;
  *(float4*)(op + 4) = c;
}

// ---------------- launch ----------------

extern "C" void kernel_launch(void* const* d_in, const int* in_sizes, int n_in,
                              void* d_out, int out_size, void* d_ws, size_t ws_size,
                              hipStream_t stream) {
  (void)n_in; (void)out_size; (void)ws_size;
  const float* x = (const float*)d_in[0];
  const void* edges = d_in[1];
  const float* W1l = (const float*)d_in[2];
  const float* W1r = (const float*)d_in[3];
  const float* b1 = (const float*)d_in[4];
  const float* W2l = (const float*)d_in[5];
  const float* W2r = (const float*)d_in[6];
  const float* b2 = (const float*)d_in[7];
  const float* W3l = (const float*)d_in[8];
  const float* W3r = (const float*)d_in[9];
  const float* b3 = (const float*)d_in[10];
  float* out = (float*)d_out;

  const int N = in_sizes[0] / 128;
  const int E = in_sizes[1] / 2;
  const int NB = (N + BSIZE - 1) >> BSHIFT;

  char* ws = (char*)d_ws;
  size_t off = 0;
  auto alloc = [&](size_t bytes) -> char* {
    char* p = ws + off;
    off = (off + bytes + 255) & ~(size_t)255;
    return p;
  };
  int* bucketCursor = (int*)alloc((size_t)NB * 4);
  unsigned* bucketed = (unsigned*)alloc((size_t)NB * CAP * 4);
  int* rowStart = (int*)alloc((size_t)N * 4);
  int* deg = (int*)alloc((size_t)N * 4);
  int* srcSorted = (int*)alloc((size_t)NB * CAP * 4);
  unsigned short* xT = (unsigned short*)alloc((size_t)N * 128 * 2);
  unsigned short* meanT = (unsigned short*)alloc((size_t)N * 128 * 2);
  unsigned short* h1T = (unsigned short*)alloc((size_t)N * 128 * 2);
  unsigned short* h2T = (unsigned short*)alloc((size_t)N * 128 * 2);
  unsigned short* y3T = (unsigned short*)alloc((size_t)N * 64 * 2);
  unsigned short* Wb1 = (unsigned short*)alloc(128 * 256 * 2);
  unsigned short* Wb2 = (unsigned short*)alloc(128 * 256 * 2);
  unsigned short* Wb3 = (unsigned short*)alloc(64 * 256 * 2);

  int gCast = NBLK(N * 64, 256) + 320;
  int gE = NBLK(E, ECHUNK);
  int gRange = NBLK(N, 128);
  int gGemm = NBLK(N, 128);

  hipMemsetAsync(bucketCursor, 0, (size_t)NB * 4, stream);
  k_cast<<<gCast, 256, 0, stream>>>(x, (unsigned*)xT, N,
                                    W1l, W1r, Wb1, W2l, W2r, Wb2, W3l, W3r, Wb3);
  k_scatter<<<gE, 256, 0, stream>>>(edges, bucketCursor, bucketed, E, NB);
  k_csr<<<NB, 256, 0, stream>>>(bucketed, bucketCursor, rowStart, deg, srcSorted, N, NB);

  // layer 1
  k_agg_slice<<<gRange * 8, 256, 0, stream>>>((const uint4*)xT, rowStart, deg, srcSorted,
                                              (uint4*)meanT, N);
  k_gemm<128, true><<<gGemm, 256, 0, stream>>>(xT, meanT, Wb1, b1, h1T, N);
  // layer 2
  k_agg_slice<<<gRange * 8, 256, 0, stream>>>((const uint4*)h1T, rowStart, deg, srcSorted,
                                              (uint4*)meanT, N);
  k_gemm<128, true><<<gGemm, 256, 0, stream>>>(h1T, meanT, Wb2, b2, h2T, N);
  // layer 3: transform-first
  k_gemm3_both<<<gGemm, 256, 0, stream>>>(h2T, Wb3, b3, out, y3T, N);
  k_agg64_slice<<<gRange * 4, 256, 0, stream>>>((const uint4*)y3T, rowStart, deg, srcSorted,
                                                out, N);
}

// Round 2
// 475.536 us; speedup vs baseline: 1.1041x; 1.1041x over previous
//
#include <hip/hip_runtime.h>
#include <hip/hip_bf16.h>
#include <cstddef>
#include <cstdint>

#define NBLK(n, b) (((n) + (b) - 1) / (b))

typedef __attribute__((ext_vector_type(8))) short short8;
typedef __attribute__((ext_vector_type(4))) float f32x4;

__device__ inline unsigned short f2bf(float f) {
  union { float f; unsigned u; } v; v.f = f;
  unsigned u = v.u;
  u += 0x7FFFu + ((u >> 16) & 1u);  // RNE
  return (unsigned short)(u >> 16);
}
__device__ inline float bflo(unsigned u) { union { unsigned u; float f; } v; v.u = u << 16; return v.f; }
__device__ inline float bfhi(unsigned u) { union { unsigned u; float f; } v; v.u = u & 0xFFFF0000u; return v.f; }

// CSR bucket sort: buckets of 512 nodes; node ids < 2^17 (N=100K).
// key = src | (localDst << 17) fits u32. Fixed-capacity padded buckets.
#define BSHIFT 9
#define BSIZE 512
#define CAPSHIFT 14
#define CAP 16384
#define ECHUNK 2048

// All bf16 feature tensors live in SLICE-TRANSPOSED layout:
//   element (node, ch) at half-index ((ch>>4) * N + node) * 16 + (ch & 15)
// i.e. T[g][N][16ch], 32 B per node per 16-ch slice. One slice = 3.2 MB -> fits
// an XCD's 4 MB L2. Aggregation dispatches slice = blockIdx.x & 7 (XCD-affine
// via %8 round-robin) so each XCD only gathers its own slice (confirmed R1:
// FETCH 179 MB -> 100 MB == compulsory).

// ---------------- cast x -> bf16 sliced layout, prep packed weights ----------------
__global__ __launch_bounds__(256) void k_cast(
    const float* __restrict__ x, unsigned* __restrict__ xT, int N,
    const float* __restrict__ W1l, const float* __restrict__ W1r, unsigned short* __restrict__ Wb1,
    const float* __restrict__ W2l, const float* __restrict__ W2r, unsigned short* __restrict__ Wb2,
    const float* __restrict__ W3l, const float* __restrict__ W3r, unsigned short* __restrict__ Wb3) {
  int t = threadIdx.x;
  int b = blockIdx.x;
  int gCast = (N * 64 + 255) >> 8;
  if (b < gCast) {
    int i = b * 256 + t;
    if (i < N * 64) {
      float2 v = *(const float2*)(x + (size_t)i * 2);
      int node = i >> 6, j = i & 63;
      // word covers channels {2j, 2j+1}; slice g = j>>3, word-in-slice = j&7
      xT[((size_t)(j >> 3) * N + node) * 8 + (j & 7)] =
          (unsigned)f2bf(v.x) | ((unsigned)f2bf(v.y) << 16);
    }
    return;
  }
  b -= gCast;
  int ii = b * 256 + t;
  const float *Wl, *Wr; unsigned short* Wb;
  if (ii < 128 * 256) { Wl = W1l; Wr = W1r; Wb = Wb1; }
  else if (ii < 256 * 256) { Wl = W2l; Wr = W2r; Wb = Wb2; ii -= 128 * 256; }
  else { Wl = W3l; Wr = W3r; Wb = Wb3; ii -= 256 * 256; }
  int nrow = ii >> 8, k = ii & 255;
  float v = (k < 128) ? Wr[nrow * 128 + k] : Wl[nrow * 128 + (k - 128)];
  Wb[ii] = f2bf(v);
}

// ---------------- edge scatter into padded buckets ----------------
__global__ __launch_bounds__(256) void k_scatter(
    const void* __restrict__ edges, int* __restrict__ bucketCursor,
    unsigned* __restrict__ bucketed, int E, int NB) {
  __shared__ int h[1024];
  __shared__ int base2[1024];
  int t = threadIdx.x;
  int b = blockIdx.x;

  const unsigned* e32 = (const unsigned*)edges;
  int is64 = 1;
#pragma unroll
  for (int i = 0; i < 16; ++i)
    if (e32[2 * i + 1] != 0u) is64 = 0;

  for (int i = t; i < NB; i += 256) h[i] = 0;
  __syncthreads();
  int base_e = b * ECHUNK;
  unsigned key[8];
  int bkt[8];
#pragma unroll
  for (int k = 0; k < 8; ++k) {
    int e = base_e + k * 256 + t;
    bkt[k] = -1;
    if (e < E) {
      int s, d;
      if (is64) {
        s = (int)((const long long*)edges)[e];
        d = (int)((const long long*)edges)[(size_t)E + e];
      } else {
        s = ((const int*)edges)[e];
        d = ((const int*)edges)[(size_t)E + e];
      }
      bkt[k] = d >> BSHIFT;
      key[k] = (unsigned)s | ((unsigned)(d & (BSIZE - 1)) << 17);
      atomicAdd(&h[bkt[k]], 1);
    }
  }
  __syncthreads();
  for (int i = t; i < NB; i += 256) {
    int c = h[i];
    base2[i] = c ? atomicAdd(&bucketCursor[i], c) : 0;
    h[i] = 0;
  }
  __syncthreads();
#pragma unroll
  for (int k = 0; k < 8; ++k) {
    if (bkt[k] >= 0) {
      int r = atomicAdd(&h[bkt[k]], 1);
      int pos = base2[bkt[k]] + r;
      if (pos < CAP)
        bucketed[((size_t)bkt[k] << CAPSHIFT) + pos] = key[k];
    }
  }
}

// ---------------- per-bucket CSR: rowStart + deg + srcSorted (padded layout) ----------------
__global__ __launch_bounds__(256) void k_csr(const unsigned* __restrict__ bucketed,
                                             const int* __restrict__ bucketCursor,
                                             int* __restrict__ rowStart, int* __restrict__ deg,
                                             int* __restrict__ srcSorted, int N, int NB) {
  __shared__ int h[512];
  __shared__ int excl[512];
  __shared__ int sd[256];
  int b = blockIdx.x;
  int t = threadIdx.x;
  int nodeBase = b << BSHIFT;
  int nNode = min(BSIZE, N - nodeBase);
  int cnt = min(bucketCursor[b], CAP);
  size_t s0 = (size_t)b << CAPSHIFT;
  h[t * 2] = 0; h[t * 2 + 1] = 0;
  __syncthreads();
  for (int i = t; i < cnt; i += 256) {
    int ld = bucketed[s0 + i] >> 17;
    atomicAdd(&h[ld], 1);
  }
  __syncthreads();
  int a0 = h[t * 2], a1 = h[t * 2 + 1];
  int s = a0 + a1;
  sd[t] = s;
  __syncthreads();
  for (int off = 1; off < 256; off <<= 1) {
    int xv = (t >= off) ? sd[t - off] : 0;
    __syncthreads();
    sd[t] += xv;
    __syncthreads();
  }
  int run = sd[t] - s;
  excl[t * 2] = run;
  excl[t * 2 + 1] = run + a0;
  if (t * 2 < nNode) {
    rowStart[nodeBase + t * 2] = (int)s0 + run;
    deg[nodeBase + t * 2] = a0;
  }
  if (t * 2 + 1 < nNode) {
    rowStart[nodeBase + t * 2 + 1] = (int)s0 + run + a0;
    deg[nodeBase + t * 2 + 1] = a1;
  }
  h[t * 2] = 0; h[t * 2 + 1] = 0;
  __syncthreads();
  for (int i = t; i < cnt; i += 256) {
    unsigned u = bucketed[s0 + i];
    int ld = u >> 17;
    int r = atomicAdd(&h[ld], 1);
    srcSorted[s0 + excl[ld] + r] = (int)(u & 0x1FFFFu);
  }
}

// ---------------- slice-sharded wave-cooperative mean aggregation (128-ch layers) ----
// grid.x = 8 * ceil(N/16); slice g = bid & 7 (XCD-affine). 4 waves/block,
// 4 nodes/wave (one per 16-lane quarter). Lane = (q in [0,4)) x (eg in [0,8))
// x (sub in [0,2)). Indices loaded coalesced per quarter + shfl-broadcast;
// 4 uint4 gathers in flight per lane; 3 shfl_xor rounds reduce 8 edge-slots.
__global__ __launch_bounds__(256) void k_agg_slice(
    const uint4* __restrict__ inT, const int* __restrict__ rowStart,
    const int* __restrict__ deg, const int* __restrict__ srcs,
    uint4* __restrict__ outT, int n) {
  int g = blockIdx.x & 7;
  int lane = threadIdx.x & 63;
  int w = threadIdx.x >> 6;
  int q = lane >> 4;
  int l15 = lane & 15;
  int eg = (lane >> 1) & 7;
  int sub = lane & 1;
  int node = (blockIdx.x >> 3) * 16 + w * 4 + q;
  bool valid = node < n;
  int nc = valid ? node : n - 1;
  int r0 = rowStart[nc];
  int dg = valid ? deg[nc] : 0;
  int r1 = r0 + dg;
  const uint4* bp = inT + (size_t)g * n * 2 + sub;
  float acc[8];
#pragma unroll
  for (int k = 0; k < 8; ++k) acc[k] = 0.f;

  for (int base = r0; base < r1; base += 32) {
    int sv0 = srcs[min(base + l15, r1 - 1)];
    int sv1 = srcs[min(base + 16 + l15, r1 - 1)];
    uint4 v[4];
    int e[4];
#pragma unroll
    for (int k = 0; k < 4; ++k) {
      int s = __shfl((k < 2) ? sv0 : sv1, q * 16 + (k & 1) * 8 + eg);
      v[k] = bp[(size_t)s * 2];
      e[k] = base + k * 8 + eg;
    }
#pragma unroll
    for (int k = 0; k < 4; ++k) {
      if (e[k] < r1) {
        acc[0] += bflo(v[k].x); acc[1] += bfhi(v[k].x);
        acc[2] += bflo(v[k].y); acc[3] += bfhi(v[k].y);
        acc[4] += bflo(v[k].z); acc[5] += bfhi(v[k].z);
        acc[6] += bflo(v[k].w); acc[7] += bfhi(v[k].w);
      }
    }
  }

#pragma unroll
  for (int k = 0; k < 8; ++k) {
    acc[k] += __shfl_xor(acc[k], 2);
    acc[k] += __shfl_xor(acc[k], 4);
    acc[k] += __shfl_xor(acc[k], 8);
  }
  if (eg == 0 && valid) {
    float sc = 1.0f / (float)max(dg, 1);
    uint4 o;
    o.x = (unsigned)f2bf(acc[0] * sc) | ((unsigned)f2bf(acc[1] * sc) << 16);
    o.y = (unsigned)f2bf(acc[2] * sc) | ((unsigned)f2bf(acc[3] * sc) << 16);
    o.z = (unsigned)f2bf(acc[4] * sc) | ((unsigned)f2bf(acc[5] * sc) << 16);
    o.w = (unsigned)f2bf(acc[6] * sc) | ((unsigned)f2bf(acc[7] * sc) << 16);
    outT[((size_t)g * n + node) * 2 + sub] = o;
  }
}

// ---------------- MFMA GEMM: out = self@Wr.T + mean@Wl.T + b (layers 1-2) ----------------
// A operands read from sliced layout; output written to sliced layout (bf16).
template <int H, bool RELU>
__global__ __launch_bounds__(256) void k_gemm(
    const unsigned short* __restrict__ selfT, const unsigned short* __restrict__ meanT,
    const unsigned short* __restrict__ Wb, const float* __restrict__ bias,
    unsigned short* __restrict__ outT, int n) {
  constexpr int TN = H / 32;
  int lane = threadIdx.x & 63;
  int w = threadIdx.x >> 6;
  int wr = w & 1, wc = w >> 1;
  int nodeBase = blockIdx.x * 128 + wr * 64;
  int colBase = wc * (H / 2);
  int l15 = lane & 15, quad = lane >> 4;

  f32x4 acc[4][TN];
#pragma unroll
  for (int t = 0; t < 4; ++t)
#pragma unroll
    for (int j = 0; j < TN; ++j) acc[t][j] = (f32x4){0.f, 0.f, 0.f, 0.f};

#pragma unroll
  for (int c = 0; c < 8; ++c) {
    const unsigned short* A = (c < 4) ? selfT : meanT;
    int ko = (c & 3) * 32 + quad * 8;
    int gk = ko >> 4;    // 16-ch slice
    int wo = ko & 15;    // 0 or 8
    short8 af[4], bfr[TN];
#pragma unroll
    for (int t = 0; t < 4; ++t) {
      int row = min(nodeBase + t * 16 + l15, n - 1);
      af[t] = *(const short8*)(A + ((size_t)gk * n + row) * 16 + wo);
    }
#pragma unroll
    for (int j = 0; j < TN; ++j) {
      int cn = colBase + j * 16 + l15;
      bfr[j] = *(const short8*)(Wb + (size_t)cn * 256 + c * 32 + quad * 8);
    }
#pragma unroll
    for (int t = 0; t < 4; ++t)
#pragma unroll
      for (int j = 0; j < TN; ++j)
        acc[t][j] = __builtin_amdgcn_mfma_f32_16x16x32_bf16(af[t], bfr[j], acc[t][j], 0, 0, 0);
  }

#pragma unroll
  for (int j = 0; j < TN; ++j) {
    int col = colBase + j * 16 + l15;
    int gc = col >> 4;  // = wc*4 + j
    float bv = bias[col];
#pragma unroll
    for (int t = 0; t < 4; ++t) {
#pragma unroll
      for (int r = 0; r < 4; ++r) {
        int row = nodeBase + t * 16 + quad * 4 + r;
        if (row < n) {
          float v = acc[t][j][r] + bv;
          if (RELU) v = fmaxf(v, 0.f);
          outT[((size_t)gc * n + row) * 16 + l15] = f2bf(v);
        }
      }
    }
  }
}

// ---------------- layer-3 combined transform: out = h2@W3r.T + b3 (fp32); y3T = h2@W3l.T (bf16 sliced) ----------------
__global__ __launch_bounds__(256) void k_gemm3_both(
    const unsigned short* __restrict__ A,    // h2T sliced
    const unsigned short* __restrict__ Wb3,  // [64][256]: self half +0, mean half +128
    const float* __restrict__ bias,
    float* __restrict__ outp, unsigned short* __restrict__ y3T, int n) {
  int lane = threadIdx.x & 63;
  int w = threadIdx.x >> 6;
  int wr = w & 1, wc = w >> 1;
  int nodeBase = blockIdx.x * 128 + wr * 64;
  int l15 = lane & 15, quad = lane >> 4;
  int woff = wc ? 128 : 0;
  f32x4 acc[4][4];
#pragma unroll
  for (int t = 0; t < 4; ++t)
#pragma unroll
    for (int j = 0; j < 4; ++j) acc[t][j] = (f32x4){0.f, 0.f, 0.f, 0.f};
#pragma unroll
  for (int c = 0; c < 4; ++c) {
    int ko = c * 32 + quad * 8;
    int gk = ko >> 4;
    int wo = ko & 15;
    short8 af[4], bfr[4];
#pragma unroll
    for (int t = 0; t < 4; ++t) {
      int row = min(nodeBase + t * 16 + l15, n - 1);
      af[t] = *(const short8*)(A + ((size_t)gk * n + row) * 16 + wo);
    }
#pragma unroll
    for (int j = 0; j < 4; ++j) {
      int cn = j * 16 + l15;
      bfr[j] = *(const short8*)(Wb3 + (size_t)cn * 256 + woff + c * 32 + quad * 8);
    }
#pragma unroll
    for (int t = 0; t < 4; ++t)
#pragma unroll
      for (int j = 0; j < 4; ++j)
        acc[t][j] = __builtin_amdgcn_mfma_f32_16x16x32_bf16(af[t], bfr[j], acc[t][j], 0, 0, 0);
  }
#pragma unroll
  for (int j = 0; j < 4; ++j) {
    int col = j * 16 + l15;
    float bv = wc ? 0.f : bias[col];
#pragma unroll
    for (int t = 0; t < 4; ++t) {
#pragma unroll
      for (int r = 0; r < 4; ++r) {
        int row = nodeBase + t * 16 + quad * 4 + r;
        if (row < n) {
          float v = acc[t][j][r] + bv;
          if (wc) y3T[((size_t)j * n + row) * 16 + l15] = f2bf(v);
          else outp[(size_t)row * 64 + col] = v;
        }
      }
    }
  }
}

// ---------------- layer-3 slice-sharded aggregate: out += mean(y3 over in-neighbors) ----
// grid.x = 4 * ceil(N/16); slice g = bid & 3 -> slice g L2-resident on XCDs {g, g+4}.
// Same wave-cooperative structure as k_agg_slice.
__global__ __launch_bounds__(256) void k_agg64_slice(
    const uint4* __restrict__ y3T, const int* __restrict__ rowStart,
    const int* __restrict__ deg, const int* __restrict__ srcs,
    float* __restrict__ outp, int n) {
  int g = blockIdx.x & 3;
  int lane = threadIdx.x & 63;
  int w = threadIdx.x >> 6;
  int q = lane >> 4;
  int l15 = lane & 15;
  int eg = (lane >> 1) & 7;
  int sub = lane & 1;
  int node = (blockIdx.x >> 2) * 16 + w * 4 + q;
  bool valid = node < n;
  int nc = valid ? node : n - 1;
  int r0 = rowStart[nc];
  int dg = valid ? deg[nc] : 0;
  int r1 = r0 + dg;
  const uint4* bp = y3T + (size_t)g * n * 2 + sub;
  float acc[8];
#pragma unroll
  for (int k = 0; k < 8; ++k) acc[k] = 0.f;

  for (int base = r0; base < r1; base += 32) {
    int sv0 = srcs[min(base + l15, r1 - 1)];
    int sv1 = srcs[min(base + 16 + l15, r1 - 1)];
    uint4 v[4];
    int e[4];
#pragma unroll
    for (int k = 0; k < 4; ++k) {
      int s = __shfl((k < 2) ? sv0 : sv1, q * 16 + (k & 1) * 8 + eg);
      v[k] = bp[(size_t)s * 2];
      e[k] = base + k * 8 + eg;
    }
#pragma unroll
    for (int k = 0; k < 4; ++k) {
      if (e[k] < r1) {
        acc[0] += bflo(v[k].x); acc[1] += bfhi(v[k].x);
        acc[2] += bflo(v[k].y); acc[3] += bfhi(v[k].y);
        acc[4] += bflo(v[k].z); acc[5] += bfhi(v[k].z);
        acc[6] += bflo(v[k].w); acc[7] += bfhi(v[k].w);
      }
    }
  }

#pragma unroll
  for (int k = 0; k < 8; ++k) {
    acc[k] += __shfl_xor(acc[k], 2);
    acc[k] += __shfl_xor(acc[k], 4);
    acc[k] += __shfl_xor(acc[k], 8);
  }
  if (eg == 0 && valid && dg > 0) {
    float sc = 1.0f / (float)dg;
    float* op = outp + (size_t)node * 64 + g * 16 + sub * 8;
    float4 a = *(float4*)op;
    float4 c = *(float4*)(op + 4);
    a.x += acc[0] * sc; a.y += acc[1] * sc; a.z += acc[2] * sc; a.w += acc[3] * sc;
    c.x += acc[4] * sc; c.y += acc[5] * sc; c.z += acc[6] * sc; c.w += acc[7] * sc;
    *(float4*)op = a;
    *(float4*)(op + 4) = c;
  }
}

// ---------------- launch ----------------

extern "C" void kernel_launch(void* const* d_in, const int* in_sizes, int n_in,
                              void* d_out, int out_size, void* d_ws, size_t ws_size,
                              hipStream_t stream) {
  (void)n_in; (void)out_size; (void)ws_size;
  const float* x = (const float*)d_in[0];
  const void* edges = d_in[1];
  const float* W1l = (const float*)d_in[2];
  const float* W1r = (const float*)d_in[3];
  const float* b1 = (const float*)d_in[4];
  const float* W2l = (const float*)d_in[5];
  const float* W2r = (const float*)d_in[6];
  const float* b2 = (const float*)d_in[7];
  const float* W3l = (const float*)d_in[8];
  const float* W3r = (const float*)d_in[9];
  const float* b3 = (const float*)d_in[10];
  float* out = (float*)d_out;

  const int N = in_sizes[0] / 128;
  const int E = in_sizes[1] / 2;
  const int NB = (N + BSIZE - 1) >> BSHIFT;

  char* ws = (char*)d_ws;
  size_t off = 0;
  auto alloc = [&](size_t bytes) -> char* {
    char* p = ws + off;
    off = (off + bytes + 255) & ~(size_t)255;
    return p;
  };
  int* bucketCursor = (int*)alloc((size_t)NB * 4);
  unsigned* bucketed = (unsigned*)alloc((size_t)NB * CAP * 4);
  int* rowStart = (int*)alloc((size_t)N * 4);
  int* deg = (int*)alloc((size_t)N * 4);
  int* srcSorted = (int*)alloc((size_t)NB * CAP * 4);
  unsigned short* xT = (unsigned short*)alloc((size_t)N * 128 * 2);
  unsigned short* meanT = (unsigned short*)alloc((size_t)N * 128 * 2);
  unsigned short* h1T = (unsigned short*)alloc((size_t)N * 128 * 2);
  unsigned short* h2T = (unsigned short*)alloc((size_t)N * 128 * 2);
  unsigned short* y3T = (unsigned short*)alloc((size_t)N * 64 * 2);
  unsigned short* Wb1 = (unsigned short*)alloc(128 * 256 * 2);
  unsigned short* Wb2 = (unsigned short*)alloc(128 * 256 * 2);
  unsigned short* Wb3 = (unsigned short*)alloc(64 * 256 * 2);

  int gCast = NBLK(N * 64, 256) + 320;
  int gE = NBLK(E, ECHUNK);
  int gAgg = NBLK(N, 16) * 8;
  int gAgg64 = NBLK(N, 16) * 4;
  int gGemm = NBLK(N, 128);

  hipMemsetAsync(bucketCursor, 0, (size_t)NB * 4, stream);
  k_cast<<<gCast, 256, 0, stream>>>(x, (unsigned*)xT, N,
                                    W1l, W1r, Wb1, W2l, W2r, Wb2, W3l, W3r, Wb3);
  k_scatter<<<gE, 256, 0, stream>>>(edges, bucketCursor, bucketed, E, NB);
  k_csr<<<NB, 256, 0, stream>>>(bucketed, bucketCursor, rowStart, deg, srcSorted, N, NB);

  // layer 1
  k_agg_slice<<<gAgg, 256, 0, stream>>>((const uint4*)xT, rowStart, deg, srcSorted,
                                        (uint4*)meanT, N);
  k_gemm<128, true><<<gGemm, 256, 0, stream>>>(xT, meanT, Wb1, b1, h1T, N);
  // layer 2
  k_agg_slice<<<gAgg, 256, 0, stream>>>((const uint4*)h1T, rowStart, deg, srcSorted,
                                        (uint4*)meanT, N);
  k_gemm<128, true><<<gGemm, 256, 0, stream>>>(h1T, meanT, Wb2, b2, h2T, N);
  // layer 3: transform-first
  k_gemm3_both<<<gGemm, 256, 0, stream>>>(h2T, Wb3, b3, out, y3T, N);
  k_agg64_slice<<<gAgg64, 256, 0, stream>>>((const uint4*)y3T, rowStart, deg, srcSorted,
                                            out, N);
}